// Round 7
// baseline (256.928 us; speedup 1.0000x reference)
//
#include <hip/hip_runtime.h>
#include <hip/hip_bf16.h>

#define MM 256
#define KK 4096
#define NN 32000
#define BN 64
#define BK 64
#define NT (KK / BK)   // 64 K-steps

typedef __bf16 bf16x8 __attribute__((ext_vector_type(8)));
typedef float f32x4 __attribute__((ext_vector_type(4)));

__device__ __forceinline__ unsigned pk(float a, float b) {
    unsigned short lo = __builtin_bit_cast(unsigned short, __float2bfloat16(a));
    unsigned short hi = __builtin_bit_cast(unsigned short, __float2bfloat16(b));
    return (unsigned)lo | ((unsigned)hi << 16);
}

// x fp32 [256][4096] -> bf16 row-major in ws (plain layout; gemm reads frags
// directly from L2/L3, no LDS staging for x)
__global__ void cvt_x_kernel(const float* __restrict__ x, unsigned short* __restrict__ xb) {
    int i = (blockIdx.x * 256 + threadIdx.x) * 8;
    float4 a = *(const float4*)(x + i);
    float4 b = *(const float4*)(x + i + 4);
    uint4 p;
    p.x = pk(a.x, a.y); p.y = pk(a.z, a.w);
    p.z = pk(b.x, b.y); p.w = pk(b.z, b.w);
    *(uint4*)(xb + i) = p;
}

// C[m][n] = sum_k x[m][k] * w[n][k]. BM=256 (W fetched exactly once), BN=64,
// grid=500. 512 thr = 8 waves, wave w owns rows [32w,32w+32) x ALL 64 cols.
// x: bf16 frags global->reg, depth-1 reg dbuf (issued 1 tile ahead, L2-hit).
// W: fp32->reg depth-2 -> pk -> LDS dbuf 2x8KB (only LDS tenant -> 16KB,
// VGPR~115 -> 16 waves/CU). One raw s_barrier/tile; all vmcnt waits are
// compiler-exact via register deps (counted, never drain-to-0 in loop).
template <bool XB>
__global__ __launch_bounds__(512, 4) void gemm_kernel(
    const unsigned short* __restrict__ xb, const float* __restrict__ xf,
    const float* __restrict__ w, float* __restrict__ out) {
    __shared__ unsigned short wt[2][4096];   // 2 x 8 KB

    const int tid  = threadIdx.x;
    const int lane = tid & 63;
    const int wid  = tid >> 6;    // 0..7 -> 32-row M slice
    const int l15  = lane & 15;
    const int lg   = lane >> 4;
    const int n0   = blockIdx.x * BN;
    const int arow = wid * 32;

    // W staging: thread -> row tid>>3 (0..63), slot tid&7 (8 floats = 32B)
    const int wrow  = tid >> 3;
    const int wslot = tid & 7;
    const float* wsrc = w + (size_t)(n0 + wrow) * KK + wslot * 8;
    const int wdst = wrow * 64 + ((wslot ^ (wrow & 7)) * 8);

    f32x4 acc[2][4];
#pragma unroll
    for (int i = 0; i < 2; ++i)
#pragma unroll
        for (int j = 0; j < 4; ++j) acc[i][j] = f32x4{0.f, 0.f, 0.f, 0.f};

    auto compute = [&](int pb, uint4 (&xc)[2][2]) {
#pragma unroll
        for (int kf = 0; kf < 2; ++kf) {
            const int c = kf * 4 + lg;
            uint4 bfr[4];
#pragma unroll
            for (int ni = 0; ni < 4; ++ni) {
                const int r = ni * 16 + l15;
                bfr[ni] = *(const uint4*)&wt[pb][r * 64 + ((c ^ (r & 7)) * 8)];
            }
#pragma unroll
            for (int mi = 0; mi < 2; ++mi)
#pragma unroll
                for (int ni = 0; ni < 4; ++ni)
                    acc[mi][ni] = __builtin_amdgcn_mfma_f32_16x16x32_bf16(
                        __builtin_bit_cast(bf16x8, xc[mi][kf]),
                        __builtin_bit_cast(bf16x8, bfr[ni]), acc[mi][ni], 0, 0, 0);
        }
    };

    if constexpr (!XB) {
        // correctness fallback (ws too small): direct global reads, no LDS
#pragma unroll 1
        for (int t = 0; t < KK / 32; ++t) {
            const int k = t * 32 + lg * 8;
            uint4 bfr[4];
#pragma unroll
            for (int ni = 0; ni < 4; ++ni) {
                const float* p = w + (size_t)(n0 + ni * 16 + l15) * KK + k;
                float4 a0 = *(const float4*)p;
                float4 a1 = *(const float4*)(p + 4);
                bfr[ni].x = pk(a0.x, a0.y); bfr[ni].y = pk(a0.z, a0.w);
                bfr[ni].z = pk(a1.x, a1.y); bfr[ni].w = pk(a1.z, a1.w);
            }
#pragma unroll
            for (int mi = 0; mi < 2; ++mi) {
                const float* p = xf + (size_t)(arow + mi * 16 + l15) * KK + k;
                float4 a0 = *(const float4*)p;
                float4 a1 = *(const float4*)(p + 4);
                uint4 af;
                af.x = pk(a0.x, a0.y); af.y = pk(a0.z, a0.w);
                af.z = pk(a1.x, a1.y); af.w = pk(a1.z, a1.w);
#pragma unroll
                for (int ni = 0; ni < 4; ++ni)
                    acc[mi][ni] = __builtin_amdgcn_mfma_f32_16x16x32_bf16(
                        __builtin_bit_cast(bf16x8, af),
                        __builtin_bit_cast(bf16x8, bfr[ni]), acc[mi][ni], 0, 0, 0);
            }
        }
    } else {
        const unsigned short* xbase = xb + (size_t)(arow + l15) * KK + lg * 8;

        float4 wrA[2], wrB[2];
        uint4 xA[2][2], xB[2][2];

        auto issueW = [&](int t, float4 (&wr)[2]) {
            const float* p = wsrc + t * BK;
            wr[0] = *(const float4*)(p);
            wr[1] = *(const float4*)(p + 4);
        };
        auto stageW = [&](int pb, float4 (&wr)[2]) {
            uint4 v;
            v.x = pk(wr[0].x, wr[0].y); v.y = pk(wr[0].z, wr[0].w);
            v.z = pk(wr[1].x, wr[1].y); v.w = pk(wr[1].z, wr[1].w);
            *(uint4*)&wt[pb][wdst] = v;
        };
        auto issueX = [&](int t, uint4 (&xc)[2][2]) {
#pragma unroll
            for (int mi = 0; mi < 2; ++mi)
#pragma unroll
                for (int kf = 0; kf < 2; ++kf)
                    xc[mi][kf] = *(const uint4*)(xbase + (size_t)mi * 16 * KK + t * BK + kf * 32);
        };

        // prologue FIFO: [W(0):4, x(0):4, W(1):4]
        issueW(0, wrA);
        issueX(0, xA);
        issueW(1, wrB);

#pragma unroll 1
        for (int t = 0; t < NT; t += 2) {
            // ---- tile t (pb=0): stageW drains W(t), keeps x(t)+W(t+1) ----
            stageW(0, wrA);
            __builtin_amdgcn_sched_barrier(0);
            asm volatile("s_waitcnt lgkmcnt(0)" ::: "memory");
            __builtin_amdgcn_s_barrier();
            {
                const int tx = (t + 1 < NT) ? t + 1 : NT - 1;
                issueX(tx, xB);
                const int tw = (t + 2 < NT) ? t + 2 : NT - 1;
                issueW(tw, wrA);
            }
            compute(0, xA);   // waits x(t); x(t+1)+W(t+2) stay in flight

            // ---- tile t+1 (pb=1) ----
            stageW(1, wrB);
            __builtin_amdgcn_sched_barrier(0);
            asm volatile("s_waitcnt lgkmcnt(0)" ::: "memory");
            __builtin_amdgcn_s_barrier();
            {
                const int tx = (t + 2 < NT) ? t + 2 : NT - 1;
                issueX(tx, xA);
                const int tw = (t + 3 < NT) ? t + 3 : NT - 1;
                issueW(tw, wrB);
            }
            compute(1, xB);
        }
    }

    // epilogue: per 16x16 tile, col = lane&15, row = (lane>>4)*4 + v
#pragma unroll
    for (int mi = 0; mi < 2; ++mi)
#pragma unroll
        for (int ni = 0; ni < 4; ++ni) {
            const int rowb = arow + mi * 16 + lg * 4;
            const int col  = n0 + ni * 16 + l15;
#pragma unroll
            for (int v = 0; v < 4; ++v)
                out[(size_t)(rowb + v) * NN + col] = acc[mi][ni][v];
        }
}

extern "C" void kernel_launch(void* const* d_in, const int* in_sizes, int n_in,
                              void* d_out, int out_size, void* d_ws, size_t ws_size,
                              hipStream_t stream) {
    const float* x = (const float*)d_in[0];
    const float* w = (const float*)d_in[1];
    float* out = (float*)d_out;
    unsigned short* xb = (unsigned short*)d_ws;

    if (ws_size >= (size_t)MM * KK * sizeof(unsigned short)) {
        cvt_x_kernel<<<512, 256, 0, stream>>>(x, xb);
        gemm_kernel<true><<<NN / BN, 512, 0, stream>>>(xb, x, w, out);
    } else {
        gemm_kernel<false><<<NN / BN, 512, 0, stream>>>(nullptr, x, w, out);
    }
}

// Round 8
// 200.604 us; speedup vs baseline: 1.2808x; 1.2808x over previous
//
#include <hip/hip_runtime.h>
#include <hip/hip_bf16.h>

#define MM 256
#define KK 4096
#define NN 32000
#define BN 64
#define BK 64
#define NT (KK / BK)   // 64 K-steps

typedef __bf16 bf16x8 __attribute__((ext_vector_type(8)));
typedef float f32x4 __attribute__((ext_vector_type(4)));

__device__ __forceinline__ unsigned pk(float a, float b) {
    unsigned short lo = __builtin_bit_cast(unsigned short, __float2bfloat16(a));
    unsigned short hi = __builtin_bit_cast(unsigned short, __float2bfloat16(b));
    return (unsigned)lo | ((unsigned)hi << 16);
}

// xb: bf16 x in FRAGMENT-MAJOR layout. For M-slice s (32 rows), tile t, frag
// f (mi=f>>1, kf=f&1), lane l: 16B chunk at ((s*64+t)*4+f)*1024 + l*16 bytes
// holds x[s*32+mi*16+(l&15)][t*64+kf*32+(l>>4)*8 .. +8). Each gemm x-load is
// one fully-contiguous 1KB dwordx4 per wave.
__global__ void cvt_x_kernel(const float* __restrict__ x, unsigned short* __restrict__ xb) {
    int g = blockIdx.x * 256 + threadIdx.x;   // 16B-chunk id, 131072 total
    int l   = g & 63;
    int f   = (g >> 6) & 3;
    int t   = (g >> 8) & 63;
    int s   = g >> 14;
    int mi  = f >> 1;
    int kf  = f & 1;
    int row = s * 32 + mi * 16 + (l & 15);
    int col = t * 64 + kf * 32 + (l >> 4) * 8;
    const float* p = x + (size_t)row * KK + col;
    float4 a = *(const float4*)p;
    float4 b = *(const float4*)(p + 4);
    uint4 v;
    v.x = pk(a.x, a.y); v.y = pk(a.z, a.w);
    v.z = pk(b.x, b.y); v.w = pk(b.z, b.w);
    *(uint4*)(xb + (size_t)g * 8) = v;
}

// C[m][n] = sum_k x[m][k] * w[n][k]. BM=256 (W fetched exactly once), BN=64,
// grid=500. 512 thr = 8 waves; wave w owns rows [32w,32w+32) x all 64 cols.
// x: frag-major bf16 from ws, global->reg depth-1 dbuf, 1KB coalesced loads,
// L2-resident, NO LDS, NO barrier dependency (per-wave private = race-free).
// W: fp32->reg depth-2 -> pk -> swizzled LDS dbuf 2x8KB (only LDS tenant).
// One raw s_barrier/tile guards W only; all waits counted via register deps.
template <bool XB>
__global__ __launch_bounds__(512, 2) void gemm_kernel(
    const unsigned short* __restrict__ xb, const float* __restrict__ xf,
    const float* __restrict__ w, float* __restrict__ out) {
    __shared__ unsigned short wt[2][4096];   // 2 x 8 KB

    const int tid  = threadIdx.x;
    const int lane = tid & 63;
    const int wid  = tid >> 6;    // 0..7 -> 32-row M slice
    const int l15  = lane & 15;
    const int lg   = lane >> 4;
    const int n0   = blockIdx.x * BN;
    const int arow = wid * 32;

    // W staging: thread -> row tid>>3 (0..63), slot tid&7 (8 floats = 32B)
    const int wrow  = tid >> 3;
    const int wslot = tid & 7;
    const float* wsrc = w + (size_t)(n0 + wrow) * KK + wslot * 8;
    const int wdst = wrow * 64 + ((wslot ^ (wrow & 7)) * 8);

    f32x4 acc[2][4];
#pragma unroll
    for (int i = 0; i < 2; ++i)
#pragma unroll
        for (int j = 0; j < 4; ++j) acc[i][j] = f32x4{0.f, 0.f, 0.f, 0.f};

    auto compute = [&](int pb, uint4 (&xc)[4]) {
#pragma unroll
        for (int kf = 0; kf < 2; ++kf) {
            const int c = kf * 4 + lg;
            uint4 bfr[4];
#pragma unroll
            for (int ni = 0; ni < 4; ++ni) {
                const int r = ni * 16 + l15;
                bfr[ni] = *(const uint4*)&wt[pb][r * 64 + ((c ^ (r & 7)) * 8)];
            }
#pragma unroll
            for (int mi = 0; mi < 2; ++mi)
#pragma unroll
                for (int ni = 0; ni < 4; ++ni)
                    acc[mi][ni] = __builtin_amdgcn_mfma_f32_16x16x32_bf16(
                        __builtin_bit_cast(bf16x8, xc[mi * 2 + kf]),
                        __builtin_bit_cast(bf16x8, bfr[ni]), acc[mi][ni], 0, 0, 0);
        }
    };

    if constexpr (!XB) {
        // correctness fallback (ws too small): direct global reads, no LDS
#pragma unroll 1
        for (int t = 0; t < KK / 32; ++t) {
            const int k = t * 32 + lg * 8;
            uint4 bfr[4];
#pragma unroll
            for (int ni = 0; ni < 4; ++ni) {
                const float* p = w + (size_t)(n0 + ni * 16 + l15) * KK + k;
                float4 a0 = *(const float4*)p;
                float4 a1 = *(const float4*)(p + 4);
                bfr[ni].x = pk(a0.x, a0.y); bfr[ni].y = pk(a0.z, a0.w);
                bfr[ni].z = pk(a1.x, a1.y); bfr[ni].w = pk(a1.z, a1.w);
            }
#pragma unroll
            for (int mi = 0; mi < 2; ++mi) {
                const float* p = xf + (size_t)(arow + mi * 16 + l15) * KK + k;
                float4 a0 = *(const float4*)p;
                float4 a1 = *(const float4*)(p + 4);
                uint4 af;
                af.x = pk(a0.x, a0.y); af.y = pk(a0.z, a0.w);
                af.z = pk(a1.x, a1.y); af.w = pk(a1.z, a1.w);
#pragma unroll
                for (int ni = 0; ni < 4; ++ni)
                    acc[mi][ni] = __builtin_amdgcn_mfma_f32_16x16x32_bf16(
                        __builtin_bit_cast(bf16x8, af),
                        __builtin_bit_cast(bf16x8, bfr[ni]), acc[mi][ni], 0, 0, 0);
            }
        }
    } else {
        // per-wave x base (byte-addressed 16B chunks): ((wid*64+t)*4+f)*1024 + lane*16
        const unsigned short* xwave = xb + ((size_t)wid * 64 * 4) * 512 + lane * 8;

        float4 wrA[2], wrB[2];
        uint4 xA[4], xB[4];

        auto issueW = [&](int t, float4 (&wr)[2]) {
            const float* p = wsrc + t * BK;
            wr[0] = *(const float4*)(p);
            wr[1] = *(const float4*)(p + 4);
        };
        auto stageW = [&](int pb, float4 (&wr)[2]) {
            uint4 v;
            v.x = pk(wr[0].x, wr[0].y); v.y = pk(wr[0].z, wr[0].w);
            v.z = pk(wr[1].x, wr[1].y); v.w = pk(wr[1].z, wr[1].w);
            *(uint4*)&wt[pb][wdst] = v;
        };
        auto issueX = [&](int t, uint4 (&xc)[4]) {
            const unsigned short* p = xwave + (size_t)t * 2048;   // 4*1024B = 2048 ushorts
#pragma unroll
            for (int f = 0; f < 4; ++f)
                xc[f] = *(const uint4*)(p + f * 512);
        };

        // prologue FIFO: [W(0):2, x(0):4, W(1):2]
        issueW(0, wrA);
        issueX(0, xA);
        issueW(1, wrB);

#pragma unroll 1
        for (int t = 0; t < NT; t += 2) {
            // ---- tile t (pb=0): stageW waits W(t), keeps x(t)+W(t+1) ----
            stageW(0, wrA);
            __builtin_amdgcn_sched_barrier(0);
            asm volatile("s_waitcnt lgkmcnt(0)" ::: "memory");
            __builtin_amdgcn_s_barrier();
            {
                const int tx = (t + 1 < NT) ? t + 1 : NT - 1;
                issueX(tx, xB);
                const int tw = (t + 2 < NT) ? t + 2 : NT - 1;
                issueW(tw, wrA);
            }
            compute(0, xA);   // waits x(t); x(t+1)+W(t+2) stay in flight

            // ---- tile t+1 (pb=1) ----
            stageW(1, wrB);
            __builtin_amdgcn_sched_barrier(0);
            asm volatile("s_waitcnt lgkmcnt(0)" ::: "memory");
            __builtin_amdgcn_s_barrier();
            {
                const int tx = (t + 2 < NT) ? t + 2 : NT - 1;
                issueX(tx, xA);
                const int tw = (t + 3 < NT) ? t + 3 : NT - 1;
                issueW(tw, wrB);
            }
            compute(1, xB);
        }
    }

    // epilogue: per 16x16 tile, col = lane&15, row = (lane>>4)*4 + v
#pragma unroll
    for (int mi = 0; mi < 2; ++mi)
#pragma unroll
        for (int ni = 0; ni < 4; ++ni) {
            const int rowb = arow + mi * 16 + lg * 4;
            const int col  = n0 + ni * 16 + l15;
#pragma unroll
            for (int v = 0; v < 4; ++v)
                out[(size_t)(rowb + v) * NN + col] = acc[mi][ni][v];
        }
}

extern "C" void kernel_launch(void* const* d_in, const int* in_sizes, int n_in,
                              void* d_out, int out_size, void* d_ws, size_t ws_size,
                              hipStream_t stream) {
    const float* x = (const float*)d_in[0];
    const float* w = (const float*)d_in[1];
    float* out = (float*)d_out;
    unsigned short* xb = (unsigned short*)d_ws;

    if (ws_size >= (size_t)MM * KK * sizeof(unsigned short)) {
        cvt_x_kernel<<<512, 256, 0, stream>>>(x, xb);
        gemm_kernel<true><<<NN / BN, 512, 0, stream>>>(xb, x, w, out);
    } else {
        gemm_kernel<false><<<NN / BN, 512, 0, stream>>>(nullptr, x, w, out);
    }
}

// Round 9
// 192.008 us; speedup vs baseline: 1.3381x; 1.0448x over previous
//
#include <hip/hip_runtime.h>
#include <hip/hip_bf16.h>

#define MM 256
#define KK 4096
#define NN 32000
#define BN 32
#define BK 32
#define NT (KK / BK)   // 128 K-steps

typedef __bf16 bf16x8 __attribute__((ext_vector_type(8)));
typedef float f32x4 __attribute__((ext_vector_type(4)));

__device__ __forceinline__ unsigned pk(float a, float b) {
    unsigned short lo = __builtin_bit_cast(unsigned short, __float2bfloat16(a));
    unsigned short hi = __builtin_bit_cast(unsigned short, __float2bfloat16(b));
    return (unsigned)lo | ((unsigned)hi << 16);
}

__device__ __forceinline__ void dma16(const unsigned short* g, unsigned short* l) {
    __builtin_amdgcn_global_load_lds(
        (const __attribute__((address_space(1))) unsigned int*)g,
        (__attribute__((address_space(3))) unsigned int*)l, 16, 0, 0);
}

// xb: tile-major [t in 0..127][row r in 0..255][slot s in 0..3], slot = 8
// ushorts, PRE-SWIZZLED: slot s of row r holds x[r][t*32 + (s^((r>>1)&3))*8).
// gemm DMAs each 16KB tile LINEARLY; swizzled ds_read recovers fragments
// conflict-free (8 distinct 4-bank starts per 16-lane group -> 2-way max).
__global__ void cvt_x_kernel(const float* __restrict__ x, unsigned short* __restrict__ xb) {
    int g = blockIdx.x * 256 + threadIdx.x;   // chunk id, 131072 total
    int s = g & 3;
    int r = (g >> 2) & 255;
    int t = g >> 10;
    int c = s ^ ((r >> 1) & 3);
    const float* p = x + (size_t)r * KK + t * BK + c * 8;
    float4 a = *(const float4*)p;
    float4 b = *(const float4*)(p + 4);
    uint4 v;
    v.x = pk(a.x, a.y); v.y = pk(a.z, a.w);
    v.z = pk(b.x, b.y); v.w = pk(b.z, b.w);
    *(uint4*)(xb + (size_t)g * 8) = v;
}

// C[m][n] = sum_k x[m][k] * w[n][k]. BM=256 (W fetched exactly once), BN=32,
// BK=32, grid=1000 -> 4 blocks/CU (36KB LDS each), 4-wave barrier domains.
// 256 thr = 4 waves; wave w owns rows [64w,64w+64) x all 32 cols.
// x: ws bf16 -> global_load_lds dbuf 2x16KB. W: fp32->reg depth-2 -> pk ->
// swizzled LDS dbuf 2x2KB. One raw s_barrier/tile; own dma drained EXACTLY
// (vmcnt(1)) before barrier; W(t+1) always in flight (never vmcnt 0 in loop).
template <bool XB>
__global__ __launch_bounds__(256, 4) void gemm_kernel(
    const unsigned short* __restrict__ xb, const float* __restrict__ xf,
    const float* __restrict__ w, float* __restrict__ out) {
    __shared__ unsigned short xs[2][8192];  // 2 x 16 KB
    __shared__ unsigned short wt[2][1024];  // 2 x 2 KB

    const int tid  = threadIdx.x;
    const int lane = tid & 63;
    const int wid  = tid >> 6;    // 0..3 -> 64-row M slice
    const int l15  = lane & 15;
    const int lg   = lane >> 4;
    const int n0   = blockIdx.x * BN;
    const int arow = wid * 64;

    // W staging: thread -> row tid>>3 (0..31), 4 floats at col (tid&7)*4
    const int wrow = tid >> 3;
    const int wc   = tid & 7;          // half-chunk index (4 floats)
    const float* wsrc = w + (size_t)(n0 + wrow) * KK + wc * 4;
    // dest: chunk c=wc>>1 at slot (c ^ ((wrow>>1)&3)), half wc&1
    const int wdst = wrow * 32 + (((wc >> 1) ^ ((wrow >> 1) & 3)) * 8) + (wc & 1) * 4;

    f32x4 acc[4][2];
#pragma unroll
    for (int i = 0; i < 4; ++i)
#pragma unroll
        for (int j = 0; j < 2; ++j) acc[i][j] = f32x4{0.f, 0.f, 0.f, 0.f};

    auto compute = [&](int pb) {
        __builtin_amdgcn_s_setprio(1);
        uint4 bfr[2];
#pragma unroll
        for (int ni = 0; ni < 2; ++ni) {
            const int r = ni * 16 + l15;
            bfr[ni] = *(const uint4*)&wt[pb][r * 32 + ((lg ^ ((r >> 1) & 3)) * 8)];
        }
        uint4 af[4];
#pragma unroll
        for (int mi = 0; mi < 4; ++mi) {
            const int r = arow + mi * 16 + l15;
            af[mi] = *(const uint4*)&xs[pb][r * 32 + ((lg ^ ((r >> 1) & 3)) * 8)];
        }
#pragma unroll
        for (int mi = 0; mi < 4; ++mi)
#pragma unroll
            for (int ni = 0; ni < 2; ++ni)
                acc[mi][ni] = __builtin_amdgcn_mfma_f32_16x16x32_bf16(
                    __builtin_bit_cast(bf16x8, af[mi]),
                    __builtin_bit_cast(bf16x8, bfr[ni]), acc[mi][ni], 0, 0, 0);
        __builtin_amdgcn_s_setprio(0);
    };

    if constexpr (!XB) {
        // correctness fallback (ws too small): direct global reads, no LDS
#pragma unroll 1
        for (int t = 0; t < NT; ++t) {
            const int k = t * BK + lg * 8;
            uint4 bfr[2];
#pragma unroll
            for (int ni = 0; ni < 2; ++ni) {
                const float* p = w + (size_t)(n0 + ni * 16 + l15) * KK + k;
                float4 a0 = *(const float4*)p;
                float4 a1 = *(const float4*)(p + 4);
                bfr[ni].x = pk(a0.x, a0.y); bfr[ni].y = pk(a0.z, a0.w);
                bfr[ni].z = pk(a1.x, a1.y); bfr[ni].w = pk(a1.z, a1.w);
            }
#pragma unroll
            for (int mi = 0; mi < 4; ++mi) {
                const float* p = xf + (size_t)(arow + mi * 16 + l15) * KK + k;
                float4 a0 = *(const float4*)p;
                float4 a1 = *(const float4*)(p + 4);
                uint4 af;
                af.x = pk(a0.x, a0.y); af.y = pk(a0.z, a0.w);
                af.z = pk(a1.x, a1.y); af.w = pk(a1.z, a1.w);
#pragma unroll
                for (int ni = 0; ni < 2; ++ni)
                    acc[mi][ni] = __builtin_amdgcn_mfma_f32_16x16x32_bf16(
                        __builtin_bit_cast(bf16x8, af),
                        __builtin_bit_cast(bf16x8, bfr[ni]), acc[mi][ni], 0, 0, 0);
            }
        }
    } else {
        float4 wrA, wrB;

        auto issueW = [&](int t, float4& wr) {
            wr = *(const float4*)(wsrc + t * BK);
        };
        auto stageW = [&](int pb, float4& wr) {
            uint2 v;
            v.x = pk(wr.x, wr.y);
            v.y = pk(wr.z, wr.w);
            *(uint2*)&wt[pb][wdst] = v;
        };
        auto issue_dma = [&](int t, int pb) {
            // 4 rounds x 256 thr x 16B = 16 KB; wave-uniform base + lane*16B
#pragma unroll
            for (int j = 0; j < 4; ++j) {
                const unsigned short* gp =
                    xb + (size_t)t * 8192 + j * 2048 + wid * 512 + lane * 8;
                unsigned short* lp = &xs[pb][j * 2048 + wid * 512];
                dma16(gp, lp);
            }
        };

        // steady-state FIFO on tile entry: [W(t):1 oldest, dma(t):4, W(t+1):1]
        auto tile_body = [&](int pb, int t, float4& wr) {
            stageW(pb, wr);                        // reg dep -> compiler drains W(t)
            __builtin_amdgcn_sched_barrier(0);
            asm volatile("s_waitcnt vmcnt(1)" ::: "memory");   // drain dma(t) fully; keep W(t+1)
            asm volatile("s_waitcnt lgkmcnt(0)" ::: "memory"); // own ds_write visible
            __builtin_amdgcn_sched_barrier(0);
            __builtin_amdgcn_s_barrier();          // xs[pb], wt[pb] published
            const int tn = (t + 1 < NT) ? t + 1 : NT - 1;
            issue_dma(tn, pb ^ 1);                 // buffer pb^1 free: compute(t-1) done
            const int tw = (t + 2 < NT) ? t + 2 : NT - 1;
            issueW(tw, wr);
            __builtin_amdgcn_sched_barrier(0);
            compute(pb);
        };

        issueW(0, wrA);
        issue_dma(0, 0);
        issueW(1, wrB);

#pragma unroll 1
        for (int t = 0; t < NT; t += 2) {
            tile_body(0, t, wrA);
            tile_body(1, t + 1, wrB);
        }
        asm volatile("s_waitcnt vmcnt(0)" ::: "memory");  // drain tail junk
    }

    // epilogue: per 16x16 tile, col = lane&15, row = (lane>>4)*4 + v
#pragma unroll
    for (int mi = 0; mi < 4; ++mi)
#pragma unroll
        for (int ni = 0; ni < 2; ++ni) {
            const int rowb = arow + mi * 16 + lg * 4;
            const int col  = n0 + ni * 16 + l15;
#pragma unroll
            for (int v = 0; v < 4; ++v)
                out[(size_t)(rowb + v) * NN + col] = acc[mi][ni][v];
        }
}

extern "C" void kernel_launch(void* const* d_in, const int* in_sizes, int n_in,
                              void* d_out, int out_size, void* d_ws, size_t ws_size,
                              hipStream_t stream) {
    const float* x = (const float*)d_in[0];
    const float* w = (const float*)d_in[1];
    float* out = (float*)d_out;
    unsigned short* xb = (unsigned short*)d_ws;

    if (ws_size >= (size_t)MM * KK * sizeof(unsigned short)) {
        cvt_x_kernel<<<512, 256, 0, stream>>>(x, xb);
        gemm_kernel<true><<<NN / BN, 256, 0, stream>>>(xb, x, w, out);
    } else {
        gemm_kernel<false><<<NN / BN, 256, 0, stream>>>(nullptr, x, w, out);
    }
}